// Round 1
// baseline (257.204 us; speedup 1.0000x reference)
//
#include <hip/hip_runtime.h>
#include <hip/hip_bf16.h>
#include <math.h>

#define N_NODES 10000
#define N_EDGES 640000
#define N_GRAPHS 64
#define DIM 128
#define NEG_SLOPE 0.01f

// ---------------- workspace layout (bytes) ----------------
// feat     : 0          .. 10,240,000   float[2][10000][128]
// resid    : 10,240,000 .. 20,480,000   float[2][10000][128]
// a_self   : 20,480,000                 float[2][10000]
// a_nb     : 20,560,000                 float[2][10000]
// deg      : 20,640,000                 int[10000]
// rowptr   : 20,688,000                 int[10001]
// cur      : 20,736,000                 int[10000]
// csr_src  : 20,784,000                 int[640000]
// feat_b16 : 23,344,000 .. 28,464,000   bf16[2][10000][128]

// ---------------- CSR build phase 1: global-atomic degree histogram ----------
// 640k atomics over 10k counters (avg 64/addr, 640 cachelines spread across L2
// channels). Order within a node's edge list doesn't matter: softmax aggregation
// is order-invariant. grid 625 x 256, one int4 per thread.
__global__ __launch_bounds__(256) void deg_hist(const int4* __restrict__ edst4,
                                                int* __restrict__ deg) {
    int i = blockIdx.x * 256 + threadIdx.x;
    int4 d = edst4[i];
    atomicAdd(&deg[d.x], 1);
    atomicAdd(&deg[d.y], 1);
    atomicAdd(&deg[d.z], 1);
    atomicAdd(&deg[d.w], 1);
}

// ---------------- CSR build phase 2: rowptr scan (+ cursor init) -------------
__global__ __launch_bounds__(1024) void scan_deg(const int* __restrict__ deg,
                                                 int* __restrict__ rowptr,
                                                 int* __restrict__ cur) {
    __shared__ int sdata[1024];
    const int tid = threadIdx.x;
    const int base = tid * 10;
    int cnt = N_NODES - base;
    if (cnt < 0) cnt = 0;
    if (cnt > 10) cnt = 10;
    int local[10];
    int s = 0;
    for (int i = 0; i < cnt; ++i) { local[i] = s; s += deg[base + i]; }
    sdata[tid] = s;
    __syncthreads();
    for (int off = 1; off < 1024; off <<= 1) {
        int v = 0;
        if (tid >= off) v = sdata[tid - off];
        __syncthreads();
        if (tid >= off) sdata[tid] += v;
        __syncthreads();
    }
    int pre = (tid == 0) ? 0 : sdata[tid - 1];
    for (int i = 0; i < cnt; ++i) {
        int r = pre + local[i];
        rowptr[base + i] = r;
        cur[base + i] = r;
    }
    if (tid == 1023) rowptr[N_NODES] = sdata[1023];
}

// ---------------- CSR build phase 3: global-atomic scatter -------------------
__global__ __launch_bounds__(256) void csr_scatter(
    const int4* __restrict__ esrc4, const int4* __restrict__ edst4,
    int* __restrict__ cur, int* __restrict__ csr_src) {
    int i = blockIdx.x * 256 + threadIdx.x;
    int4 s = esrc4[i];
    int4 d = edst4[i];
    csr_src[atomicAdd(&cur[d.x], 1)] = s.x;
    csr_src[atomicAdd(&cur[d.y], 1)] = s.y;
    csr_src[atomicAdd(&cur[d.z], 1)] = s.z;
    csr_src[atomicAdd(&cur[d.w], 1)] = s.w;
}

// ---------------- GEMM: out[n][j] = sum_k x[n][k]*W[j][k] (+bias) ----------------
// grid (ceil(N/64), 2, 4), block 256.  z: bit0 = which (0=feat,1=resid), bit1 = gat block
// which==0 epilogue also emits bf16 feat + partial a_self/a_nb via atomics.
__device__ __forceinline__ unsigned short f2bf(float f) {
    __hip_bfloat16 h = __float2bfloat16(f);
    return *reinterpret_cast<unsigned short*>(&h);
}

__global__ __launch_bounds__(256) void gemm_xwT(
    const float* __restrict__ x, const float* __restrict__ Wfc,
    const float* __restrict__ bfc, const float* __restrict__ Wres,
    float* __restrict__ feat, float* __restrict__ resid,
    unsigned short* __restrict__ feat_b16,
    const float* __restrict__ wl, const float* __restrict__ wr,
    float* __restrict__ a_self, float* __restrict__ a_nb) {
    const int which = blockIdx.z & 1;
    const int b = blockIdx.z >> 1;
    const float* __restrict__ W = (which ? Wres : Wfc) + b * DIM * DIM;
    float* __restrict__ out = (which ? resid : feat) + (size_t)b * N_NODES * DIM;
    const int n0 = blockIdx.x * 64;
    const int j0 = blockIdx.y * 64;

    __shared__ float xs[32][68];
    __shared__ float wsh[32][68];

    const int t = threadIdx.x;
    const int tj = t & 15;
    const int tn = t >> 4;
    const int r = t >> 2;
    const int q = t & 3;

    float acc[4][4];
#pragma unroll
    for (int i = 0; i < 4; ++i)
#pragma unroll
        for (int j = 0; j < 4; ++j) acc[i][j] = 0.f;

    for (int kc = 0; kc < DIM; kc += 32) {
        {
            float v[8];
            int n = n0 + r;
            if (n < N_NODES) {
                const float* p = x + (size_t)n * DIM + kc + q * 8;
                float4 v0 = *reinterpret_cast<const float4*>(p);
                float4 v1 = *reinterpret_cast<const float4*>(p + 4);
                v[0] = v0.x; v[1] = v0.y; v[2] = v0.z; v[3] = v0.w;
                v[4] = v1.x; v[5] = v1.y; v[6] = v1.z; v[7] = v1.w;
            } else {
#pragma unroll
                for (int m = 0; m < 8; ++m) v[m] = 0.f;
            }
#pragma unroll
            for (int m = 0; m < 8; ++m) xs[q * 8 + m][r] = v[m];

            const float* pw = W + (size_t)(j0 + r) * DIM + kc + q * 8;
            float4 w0 = *reinterpret_cast<const float4*>(pw);
            float4 w1 = *reinterpret_cast<const float4*>(pw + 4);
            float wv[8] = {w0.x, w0.y, w0.z, w0.w, w1.x, w1.y, w1.z, w1.w};
#pragma unroll
            for (int m = 0; m < 8; ++m) wsh[q * 8 + m][r] = wv[m];
        }
        __syncthreads();

#pragma unroll
        for (int k = 0; k < 32; ++k) {
            float4 xv = *reinterpret_cast<const float4*>(&xs[k][4 * tn]);
            float4 wv = *reinterpret_cast<const float4*>(&wsh[k][4 * tj]);
            float xa[4] = {xv.x, xv.y, xv.z, xv.w};
            float wa[4] = {wv.x, wv.y, wv.z, wv.w};
#pragma unroll
            for (int i = 0; i < 4; ++i)
#pragma unroll
                for (int j = 0; j < 4; ++j) acc[i][j] += xa[i] * wa[j];
        }
        __syncthreads();
    }

    float wlv[4], wrv[4];
    if (!which) {
#pragma unroll
        for (int k = 0; k < 4; ++k) {
            wlv[k] = wl[b * DIM + j0 + tj * 4 + k];
            wrv[k] = wr[b * DIM + j0 + tj * 4 + k];
        }
    }

#pragma unroll
    for (int i = 0; i < 4; ++i) {
        int n = n0 + tn * 4 + i;
        int j = j0 + tj * 4;
        float4 o;
        o.x = acc[i][0]; o.y = acc[i][1]; o.z = acc[i][2]; o.w = acc[i][3];
        if (!which) {
            const float* bias = bfc + b * DIM + j;
            o.x += bias[0]; o.y += bias[1]; o.z += bias[2]; o.w += bias[3];
        }
        if (n < N_NODES) {
            *reinterpret_cast<float4*>(out + (size_t)n * DIM + j) = o;
            if (!which) {
                ushort4 u;
                u.x = f2bf(o.x); u.y = f2bf(o.y); u.z = f2bf(o.z); u.w = f2bf(o.w);
                *reinterpret_cast<ushort4*>(
                    feat_b16 + ((size_t)b * N_NODES + n) * DIM + j) = u;
            }
        }
        if (!which) {
            // partial attention scalars over this block's 64 j-channels
            float ps = o.x * wlv[0] + o.y * wlv[1] + o.z * wlv[2] + o.w * wlv[3];
            float pr = o.x * wrv[0] + o.y * wrv[1] + o.z * wrv[2] + o.w * wrv[3];
#pragma unroll
            for (int off = 8; off > 0; off >>= 1) {
                ps += __shfl_xor(ps, off, 64);
                pr += __shfl_xor(pr, off, 64);
            }
            if (tj == 0 && n < N_NODES) {
                atomicAdd(&a_self[b * N_NODES + n], ps);
                atomicAdd(&a_nb[b * N_NODES + n], pr);
            }
        }
    }
}

// ---------------- softmax + weighted aggregation + residual + relu ----------------
// grid (2500, 2), block 256 = 4 waves, one node per wave. Single pass (no max:
// scores bounded ~|s|<20 << 88, exp(s) safe in fp32; softmax shift-invariant).
__global__ __launch_bounds__(256) void aggregate(
    const unsigned short* __restrict__ feat_b16, const float* __restrict__ resid,
    const float* __restrict__ a_self, const float* __restrict__ a_nb,
    const int* __restrict__ rowptr, const int* __restrict__ csr_src,
    float* __restrict__ out) {
    const int wave = threadIdx.x >> 6;
    const int lane = threadIdx.x & 63;
    const int n = blockIdx.x * 4 + wave;
    const int b = blockIdx.y;
    const int q = lane >> 4;     // edge slot within group of 4
    const int l16 = lane & 15;   // covers channels [l16*8, l16*8+8)
    const int start = rowptr[n];
    const int end = rowptr[n + 1];

    const float* __restrict__ anb = a_nb + b * N_NODES;
    const uint4* __restrict__ fb =
        reinterpret_cast<const uint4*>(feat_b16 + (size_t)b * N_NODES * DIM);
    const float asl = a_self[b * N_NODES + n];

    float acc[8];
#pragma unroll
    for (int k = 0; k < 8; ++k) acc[k] = 0.f;
    float dpart = 0.f;

    for (int c = start; c < end; c += 64) {
        int j = c + lane;
        float e = 0.f;
        int src = 0;
        if (j < end) {
            src = csr_src[j];
            float s = asl + anb[src];
            s = (s >= 0.f) ? s : NEG_SLOPE * s;
            e = __expf(s);
        }
        dpart += e;
        int cnt = end - c;
        if (cnt > 64) cnt = 64;
        int iters = (cnt + 3) >> 2;

        float w0 = __shfl(e, q, 64);
        int s0 = __shfl(src, q, 64);
        uint4 f0 = fb[(size_t)s0 * 16 + l16];

        for (int i2 = 0; i2 < iters - 1; ++i2) {
            int idx = (i2 + 1) * 4 + q;
            float w1 = __shfl(e, idx, 64);
            int s1 = __shfl(src, idx, 64);
            uint4 f1 = fb[(size_t)s1 * 16 + l16];
#pragma unroll
            for (int k = 0; k < 4; ++k) {
                unsigned int u = (&f0.x)[k];
                float lo = __uint_as_float(u << 16);
                float hi = __uint_as_float(u & 0xffff0000u);
                acc[2 * k]     += w0 * lo;
                acc[2 * k + 1] += w0 * hi;
            }
            w0 = w1; f0 = f1;
        }
#pragma unroll
        for (int k = 0; k < 4; ++k) {
            unsigned int u = (&f0.x)[k];
            float lo = __uint_as_float(u << 16);
            float hi = __uint_as_float(u & 0xffff0000u);
            acc[2 * k]     += w0 * lo;
            acc[2 * k + 1] += w0 * hi;
        }
    }

#pragma unroll
    for (int k = 0; k < 8; ++k) {
        acc[k] += __shfl_xor(acc[k], 16, 64);
        acc[k] += __shfl_xor(acc[k], 32, 64);
    }
    float denom = dpart;
#pragma unroll
    for (int off = 32; off > 0; off >>= 1) denom += __shfl_xor(denom, off, 64);

    if (q == 0) {
        float inv = (end > start) ? 1.f / denom : 0.f;
        const float4* rr = reinterpret_cast<const float4*>(
            resid + ((size_t)b * N_NODES + n) * DIM);
        float4 r0 = rr[l16 * 2];
        float4 r1 = rr[l16 * 2 + 1];
        float4 o0, o1;
        o0.x = fmaxf(acc[0] * inv + r0.x, 0.f);
        o0.y = fmaxf(acc[1] * inv + r0.y, 0.f);
        o0.z = fmaxf(acc[2] * inv + r0.z, 0.f);
        o0.w = fmaxf(acc[3] * inv + r0.w, 0.f);
        o1.x = fmaxf(acc[4] * inv + r1.x, 0.f);
        o1.y = fmaxf(acc[5] * inv + r1.y, 0.f);
        o1.z = fmaxf(acc[6] * inv + r1.z, 0.f);
        o1.w = fmaxf(acc[7] * inv + r1.w, 0.f);
        float4* po = reinterpret_cast<float4*>(out + (size_t)n * (2 * DIM) + b * DIM);
        po[l16 * 2] = o0;
        po[l16 * 2 + 1] = o1;
    }
}

// ---------------- per-graph sum pooling ----------------
__device__ int lower_bound_dev(const int* __restrict__ a, int n, int key) {
    int lo = 0, hi = n;
    while (lo < hi) {
        int mid = (lo + hi) >> 1;
        if (a[mid] < key) lo = mid + 1;
        else hi = mid;
    }
    return lo;
}

__global__ __launch_bounds__(256) void pool_graphs(
    const float* __restrict__ h, const int* __restrict__ gids,
    float* __restrict__ phis) {
    const int g = blockIdx.x;
    const int chunk = blockIdx.y;
    const int tid = threadIdx.x;
    int lo = lower_bound_dev(gids, N_NODES, g);
    int hi = lower_bound_dev(gids, N_NODES, g + 1);
    float acc = 0.f;
    for (int n = lo + chunk; n < hi; n += 16) acc += h[(size_t)n * (2 * DIM) + tid];
    if (acc != 0.f) atomicAdd(&phis[(size_t)g * (2 * DIM) + tid], acc);
}

extern "C" void kernel_launch(void* const* d_in, const int* in_sizes, int n_in,
                              void* d_out, int out_size, void* d_ws, size_t ws_size,
                              hipStream_t stream) {
    const float* x    = (const float*)d_in[0];
    const int* esrc   = (const int*)d_in[1];
    const int* edst   = (const int*)d_in[2];
    const int* gids   = (const int*)d_in[3];
    const float* Wfc  = (const float*)d_in[4];
    const float* bfc  = (const float*)d_in[5];
    const float* wl   = (const float*)d_in[6];
    const float* wr   = (const float*)d_in[7];
    const float* Wres = (const float*)d_in[8];
    float* out = (float*)d_out;

    char* ws = (char*)d_ws;
    float* feat    = (float*)(ws + 0);
    float* resid   = (float*)(ws + 10240000);
    float* a_self  = (float*)(ws + 20480000);
    float* a_nb    = (float*)(ws + 20560000);
    int*   deg     = (int*)(ws + 20640000);
    int*   rowptr  = (int*)(ws + 20688000);
    int*   cur     = (int*)(ws + 20736000);
    int*   csr_src = (int*)(ws + 20784000);
    unsigned short* feat_b16 = (unsigned short*)(ws + 23344000);

    float* phis = out + (size_t)N_NODES * 2 * DIM;

    // one-time side stream + fork/join events (created outside any capture on
    // the first verify call, reused by every subsequent call / graph capture)
    static hipStream_t s2 = nullptr;
    static hipEvent_t evFork = nullptr, evJoin = nullptr;
    if (s2 == nullptr) {
        hipStreamCreateWithFlags(&s2, hipStreamNonBlocking);
        hipEventCreateWithFlags(&evFork, hipEventDisableTiming);
        hipEventCreateWithFlags(&evJoin, hipEventDisableTiming);
    }

    // zero a_self + a_nb + deg (contiguous 200,000 B) and phis
    hipMemsetAsync(a_self, 0, 200000, stream);
    hipMemsetAsync(phis, 0, N_GRAPHS * 2 * DIM * sizeof(float), stream);

    // fork: CSR chain (edges only) runs concurrently with the GEMM chain
    hipEventRecord(evFork, stream);
    hipStreamWaitEvent(s2, evFork, 0);

    deg_hist<<<N_EDGES / 4 / 256, 256, 0, s2>>>((const int4*)edst, deg);
    scan_deg<<<1, 1024, 0, s2>>>(deg, rowptr, cur);
    csr_scatter<<<N_EDGES / 4 / 256, 256, 0, s2>>>(
        (const int4*)esrc, (const int4*)edst, cur, csr_src);
    hipEventRecord(evJoin, s2);

    gemm_xwT<<<dim3((N_NODES + 63) / 64, 2, 4), 256, 0, stream>>>(
        x, Wfc, bfc, Wres, feat, resid, feat_b16, wl, wr, a_self, a_nb);

    // join: aggregate needs both chains
    hipStreamWaitEvent(stream, evJoin, 0);
    aggregate<<<dim3(2500, 2), 256, 0, stream>>>(
        feat_b16, resid, a_self, a_nb, rowptr, csr_src, out);
    pool_graphs<<<dim3(N_GRAPHS, 16), 256, 0, stream>>>(out, gids, phis);
}

// Round 2
// 198.387 us; speedup vs baseline: 1.2965x; 1.2965x over previous
//
#include <hip/hip_runtime.h>
#include <hip/hip_bf16.h>
#include <math.h>

#define N_NODES 10000
#define N_EDGES 640000
#define N_GRAPHS 64
#define DIM 128
#define NEG_SLOPE 0.01f
#define NB_CSR 128            // histogram partitions (5000 edges each)
#define EDGES_PER_BLK (N_EDGES / NB_CSR)

// ---------------- workspace layout (bytes) ----------------
// feat     : 0          .. 10,240,000   float[2][10000][128]
// resid    : 10,240,000 .. 20,480,000   float[2][10000][128]
// a_self   : 20,480,000                 float[2][10000]
// a_nb     : 20,560,000                 float[2][10000]
// deg      : 20,640,000                 int[10000]
// rowptr   : 20,688,000                 int[10001]
// csr_src  : 20,784,000                 int[640000]
// feat_b16 : 23,344,000 .. 28,464,000   bf16[2][10000][128]
// bh       : 28,464,000 .. 33,584,000   int[128][10000] (hist -> in-place excl. offsets)

__device__ __forceinline__ unsigned short f2bf(float f) {
    __hip_bfloat16 h = __float2bfloat16(f);
    return *reinterpret_cast<unsigned short*>(&h);
}

// ---------------- fused GEMM + CSR histogram ----------------
// grid (157, 2, 5), block 256.
//   z in {0..3}: GEMM  out[n][j] = sum_k x[n][k]*W[j][k] (+bias)
//                z bit0 = which (0=feat,1=resid), bit1 = gat block.
//                which==0 epilogue also emits bf16 feat + partial a_self/a_nb.
//   z == 4    : per-partition degree histogram (blk = x*2+y, first 128 work).
//               Independent of the GEMM, rides along in the same dispatch so
//               its ~10us hides under the GEMM's compute.
// LDS union: GEMM staging 17,408 B | packed 2x16-bit histogram 20,000 B.
__global__ __launch_bounds__(256) void gemm_hist(
    const float* __restrict__ x, const float* __restrict__ Wfc,
    const float* __restrict__ bfc, const float* __restrict__ Wres,
    float* __restrict__ feat, float* __restrict__ resid,
    unsigned short* __restrict__ feat_b16,
    const float* __restrict__ wl, const float* __restrict__ wr,
    float* __restrict__ a_self, float* __restrict__ a_nb,
    const int4* __restrict__ edst4, int* __restrict__ bh) {
    __shared__ __align__(16) char smem[20032];

    if (blockIdx.z == 4) {
        // ---- histogram path: packed counters, count<=5000 fits 16 bits ----
        const int blk = blockIdx.x * 2 + blockIdx.y;
        if (blk >= NB_CSR) return;
        unsigned int* hist = reinterpret_cast<unsigned int*>(smem);
        const int t = threadIdx.x;
        for (int i = t; i < N_NODES / 2; i += 256) hist[i] = 0u;
        __syncthreads();
        const int base4 = blk * (EDGES_PER_BLK / 4);
        for (int i = t; i < EDGES_PER_BLK / 4; i += 256) {
            int4 d = edst4[base4 + i];
            atomicAdd(&hist[d.x >> 1], 1u << ((d.x & 1) << 4));
            atomicAdd(&hist[d.y >> 1], 1u << ((d.y & 1) << 4));
            atomicAdd(&hist[d.z >> 1], 1u << ((d.z & 1) << 4));
            atomicAdd(&hist[d.w >> 1], 1u << ((d.w & 1) << 4));
        }
        __syncthreads();
        int* dst = bh + (size_t)blk * N_NODES;
        for (int n = t; n < N_NODES; n += 256)
            dst[n] = (int)((hist[n >> 1] >> ((n & 1) << 4)) & 0xffffu);
        return;
    }

    // ---- GEMM path (identical math to the proven round-0 gemm_xwT) ----
    float (*xs)[68] = reinterpret_cast<float (*)[68]>(smem);
    float (*wsh)[68] = reinterpret_cast<float (*)[68]>(smem + 8704);

    const int which = blockIdx.z & 1;
    const int b = blockIdx.z >> 1;
    const float* __restrict__ W = (which ? Wres : Wfc) + b * DIM * DIM;
    float* __restrict__ out = (which ? resid : feat) + (size_t)b * N_NODES * DIM;
    const int n0 = blockIdx.x * 64;
    const int j0 = blockIdx.y * 64;

    const int t = threadIdx.x;
    const int tj = t & 15;
    const int tn = t >> 4;
    const int r = t >> 2;
    const int q = t & 3;

    float acc[4][4];
#pragma unroll
    for (int i = 0; i < 4; ++i)
#pragma unroll
        for (int j = 0; j < 4; ++j) acc[i][j] = 0.f;

    for (int kc = 0; kc < DIM; kc += 32) {
        {
            float v[8];
            int n = n0 + r;
            if (n < N_NODES) {
                const float* p = x + (size_t)n * DIM + kc + q * 8;
                float4 v0 = *reinterpret_cast<const float4*>(p);
                float4 v1 = *reinterpret_cast<const float4*>(p + 4);
                v[0] = v0.x; v[1] = v0.y; v[2] = v0.z; v[3] = v0.w;
                v[4] = v1.x; v[5] = v1.y; v[6] = v1.z; v[7] = v1.w;
            } else {
#pragma unroll
                for (int m = 0; m < 8; ++m) v[m] = 0.f;
            }
#pragma unroll
            for (int m = 0; m < 8; ++m) xs[q * 8 + m][r] = v[m];

            const float* pw = W + (size_t)(j0 + r) * DIM + kc + q * 8;
            float4 w0 = *reinterpret_cast<const float4*>(pw);
            float4 w1 = *reinterpret_cast<const float4*>(pw + 4);
            float wv[8] = {w0.x, w0.y, w0.z, w0.w, w1.x, w1.y, w1.z, w1.w};
#pragma unroll
            for (int m = 0; m < 8; ++m) wsh[q * 8 + m][r] = wv[m];
        }
        __syncthreads();

#pragma unroll
        for (int k = 0; k < 32; ++k) {
            float4 xv = *reinterpret_cast<const float4*>(&xs[k][4 * tn]);
            float4 wv = *reinterpret_cast<const float4*>(&wsh[k][4 * tj]);
            float xa[4] = {xv.x, xv.y, xv.z, xv.w};
            float wa[4] = {wv.x, wv.y, wv.z, wv.w};
#pragma unroll
            for (int i = 0; i < 4; ++i)
#pragma unroll
                for (int j = 0; j < 4; ++j) acc[i][j] += xa[i] * wa[j];
        }
        __syncthreads();
    }

    float wlv[4], wrv[4];
    if (!which) {
#pragma unroll
        for (int k = 0; k < 4; ++k) {
            wlv[k] = wl[b * DIM + j0 + tj * 4 + k];
            wrv[k] = wr[b * DIM + j0 + tj * 4 + k];
        }
    }

#pragma unroll
    for (int i = 0; i < 4; ++i) {
        int n = n0 + tn * 4 + i;
        int j = j0 + tj * 4;
        float4 o;
        o.x = acc[i][0]; o.y = acc[i][1]; o.z = acc[i][2]; o.w = acc[i][3];
        if (!which) {
            const float* bias = bfc + b * DIM + j;
            o.x += bias[0]; o.y += bias[1]; o.z += bias[2]; o.w += bias[3];
        }
        if (n < N_NODES) {
            *reinterpret_cast<float4*>(out + (size_t)n * DIM + j) = o;
            if (!which) {
                ushort4 u;
                u.x = f2bf(o.x); u.y = f2bf(o.y); u.z = f2bf(o.z); u.w = f2bf(o.w);
                *reinterpret_cast<ushort4*>(
                    feat_b16 + ((size_t)b * N_NODES + n) * DIM + j) = u;
            }
        }
        if (!which) {
            float ps = o.x * wlv[0] + o.y * wlv[1] + o.z * wlv[2] + o.w * wlv[3];
            float pr = o.x * wrv[0] + o.y * wrv[1] + o.z * wrv[2] + o.w * wrv[3];
#pragma unroll
            for (int off = 8; off > 0; off >>= 1) {
                ps += __shfl_xor(ps, off, 64);
                pr += __shfl_xor(pr, off, 64);
            }
            if (tj == 0 && n < N_NODES) {
                atomicAdd(&a_self[b * N_NODES + n], ps);
                atomicAdd(&a_nb[b * N_NODES + n], pr);
            }
        }
    }
}

// ---------------- CSR build: per-node scan over partitions (LDS-staged) -------
// bh[blk][n] becomes exclusive prefix (within node n, over blk); deg[n] = total.
// Each thread owns one node column; the 128 global loads are issued up front
// (coalesced 512B rows, deep MLP) instead of round-0's dependent rmw chain.
__global__ __launch_bounds__(128) void csr_node_scan(int* __restrict__ bh,
                                                     int* __restrict__ deg) {
    __shared__ int tile[NB_CSR][128];   // 64 KB
    const int tid = threadIdx.x;
    const int n = blockIdx.x * 128 + tid;
    const bool ok = (n < N_NODES);
#pragma unroll 8
    for (int r = 0; r < NB_CSR; ++r)
        tile[r][tid] = ok ? bh[(size_t)r * N_NODES + n] : 0;
    __syncthreads();
    int run = 0;
#pragma unroll 8
    for (int r = 0; r < NB_CSR; ++r) {
        int v = tile[r][tid];
        tile[r][tid] = run;
        run += v;
    }
    if (ok) {
        deg[n] = run;
#pragma unroll 8
        for (int r = 0; r < NB_CSR; ++r)
            bh[(size_t)r * N_NODES + n] = tile[r][tid];
    }
}

// ---------------- CSR build: rowptr scan ----------------
__global__ __launch_bounds__(1024) void scan_deg(const int* __restrict__ deg,
                                                 int* __restrict__ rowptr) {
    __shared__ int sdata[1024];
    const int tid = threadIdx.x;
    const int base = tid * 10;
    int cnt = N_NODES - base;
    if (cnt < 0) cnt = 0;
    if (cnt > 10) cnt = 10;
    int local[10];
    int s = 0;
    for (int i = 0; i < cnt; ++i) { local[i] = s; s += deg[base + i]; }
    sdata[tid] = s;
    __syncthreads();
    for (int off = 1; off < 1024; off <<= 1) {
        int v = 0;
        if (tid >= off) v = sdata[tid - off];
        __syncthreads();
        if (tid >= off) sdata[tid] += v;
        __syncthreads();
    }
    int pre = (tid == 0) ? 0 : sdata[tid - 1];
    for (int i = 0; i < cnt; ++i) rowptr[base + i] = pre + local[i];
    if (tid == 1023) rowptr[N_NODES] = sdata[1023];
}

// ---------------- CSR build: scatter via LDS cursors ----------------
__global__ __launch_bounds__(512) void csr_scatter(
    const int4* __restrict__ esrc4, const int4* __restrict__ edst4,
    const int* __restrict__ rowptr, const int* __restrict__ bh,
    int* __restrict__ csr_src) {
    __shared__ int cur[N_NODES];
    const int blk = blockIdx.x;
    const int t = threadIdx.x;
    const int* boff = bh + (size_t)blk * N_NODES;
    for (int n = t; n < N_NODES; n += 512) cur[n] = rowptr[n] + boff[n];
    __syncthreads();
    const int base4 = blk * (EDGES_PER_BLK / 4);
    for (int i = t; i < EDGES_PER_BLK / 4; i += 512) {
        int4 s = esrc4[base4 + i];
        int4 d = edst4[base4 + i];
        csr_src[atomicAdd(&cur[d.x], 1)] = s.x;
        csr_src[atomicAdd(&cur[d.y], 1)] = s.y;
        csr_src[atomicAdd(&cur[d.z], 1)] = s.z;
        csr_src[atomicAdd(&cur[d.w], 1)] = s.w;
    }
}

// ---------------- softmax + weighted aggregation + residual + relu ----------------
// grid (2500, 2), block 256 = 4 waves, one node per wave. Single pass (no max:
// scores bounded ~|s|<20 << 88, exp(s) safe in fp32; softmax shift-invariant).
__global__ __launch_bounds__(256) void aggregate(
    const unsigned short* __restrict__ feat_b16, const float* __restrict__ resid,
    const float* __restrict__ a_self, const float* __restrict__ a_nb,
    const int* __restrict__ rowptr, const int* __restrict__ csr_src,
    float* __restrict__ out) {
    const int wave = threadIdx.x >> 6;
    const int lane = threadIdx.x & 63;
    const int n = blockIdx.x * 4 + wave;
    const int b = blockIdx.y;
    const int q = lane >> 4;     // edge slot within group of 4
    const int l16 = lane & 15;   // covers channels [l16*8, l16*8+8)
    const int start = rowptr[n];
    const int end = rowptr[n + 1];

    const float* __restrict__ anb = a_nb + b * N_NODES;
    const uint4* __restrict__ fb =
        reinterpret_cast<const uint4*>(feat_b16 + (size_t)b * N_NODES * DIM);
    const float asl = a_self[b * N_NODES + n];

    float acc[8];
#pragma unroll
    for (int k = 0; k < 8; ++k) acc[k] = 0.f;
    float dpart = 0.f;

    for (int c = start; c < end; c += 64) {
        int j = c + lane;
        float e = 0.f;
        int src = 0;
        if (j < end) {
            src = csr_src[j];
            float s = asl + anb[src];
            s = (s >= 0.f) ? s : NEG_SLOPE * s;
            e = __expf(s);
        }
        dpart += e;
        int cnt = end - c;
        if (cnt > 64) cnt = 64;
        int iters = (cnt + 3) >> 2;

        float w0 = __shfl(e, q, 64);
        int s0 = __shfl(src, q, 64);
        uint4 f0 = fb[(size_t)s0 * 16 + l16];

        for (int i2 = 0; i2 < iters - 1; ++i2) {
            int idx = (i2 + 1) * 4 + q;
            float w1 = __shfl(e, idx, 64);
            int s1 = __shfl(src, idx, 64);
            uint4 f1 = fb[(size_t)s1 * 16 + l16];
#pragma unroll
            for (int k = 0; k < 4; ++k) {
                unsigned int u = (&f0.x)[k];
                float lo = __uint_as_float(u << 16);
                float hi = __uint_as_float(u & 0xffff0000u);
                acc[2 * k]     += w0 * lo;
                acc[2 * k + 1] += w0 * hi;
            }
            w0 = w1; f0 = f1;
        }
#pragma unroll
        for (int k = 0; k < 4; ++k) {
            unsigned int u = (&f0.x)[k];
            float lo = __uint_as_float(u << 16);
            float hi = __uint_as_float(u & 0xffff0000u);
            acc[2 * k]     += w0 * lo;
            acc[2 * k + 1] += w0 * hi;
        }
    }

#pragma unroll
    for (int k = 0; k < 8; ++k) {
        acc[k] += __shfl_xor(acc[k], 16, 64);
        acc[k] += __shfl_xor(acc[k], 32, 64);
    }
    float denom = dpart;
#pragma unroll
    for (int off = 32; off > 0; off >>= 1) denom += __shfl_xor(denom, off, 64);

    if (q == 0) {
        float inv = (end > start) ? 1.f / denom : 0.f;
        const float4* rr = reinterpret_cast<const float4*>(
            resid + ((size_t)b * N_NODES + n) * DIM);
        float4 r0 = rr[l16 * 2];
        float4 r1 = rr[l16 * 2 + 1];
        float4 o0, o1;
        o0.x = fmaxf(acc[0] * inv + r0.x, 0.f);
        o0.y = fmaxf(acc[1] * inv + r0.y, 0.f);
        o0.z = fmaxf(acc[2] * inv + r0.z, 0.f);
        o0.w = fmaxf(acc[3] * inv + r0.w, 0.f);
        o1.x = fmaxf(acc[4] * inv + r1.x, 0.f);
        o1.y = fmaxf(acc[5] * inv + r1.y, 0.f);
        o1.z = fmaxf(acc[6] * inv + r1.z, 0.f);
        o1.w = fmaxf(acc[7] * inv + r1.w, 0.f);
        float4* po = reinterpret_cast<float4*>(out + (size_t)n * (2 * DIM) + b * DIM);
        po[l16 * 2] = o0;
        po[l16 * 2 + 1] = o1;
    }
}

// ---------------- per-graph sum pooling ----------------
__device__ int lower_bound_dev(const int* __restrict__ a, int n, int key) {
    int lo = 0, hi = n;
    while (lo < hi) {
        int mid = (lo + hi) >> 1;
        if (a[mid] < key) lo = mid + 1;
        else hi = mid;
    }
    return lo;
}

__global__ __launch_bounds__(256) void pool_graphs(
    const float* __restrict__ h, const int* __restrict__ gids,
    float* __restrict__ phis) {
    const int g = blockIdx.x;
    const int chunk = blockIdx.y;
    const int tid = threadIdx.x;
    int lo = lower_bound_dev(gids, N_NODES, g);
    int hi = lower_bound_dev(gids, N_NODES, g + 1);
    float acc = 0.f;
    for (int n = lo + chunk; n < hi; n += 16) acc += h[(size_t)n * (2 * DIM) + tid];
    if (acc != 0.f) atomicAdd(&phis[(size_t)g * (2 * DIM) + tid], acc);
}

extern "C" void kernel_launch(void* const* d_in, const int* in_sizes, int n_in,
                              void* d_out, int out_size, void* d_ws, size_t ws_size,
                              hipStream_t stream) {
    const float* x    = (const float*)d_in[0];
    const int* esrc   = (const int*)d_in[1];
    const int* edst   = (const int*)d_in[2];
    const int* gids   = (const int*)d_in[3];
    const float* Wfc  = (const float*)d_in[4];
    const float* bfc  = (const float*)d_in[5];
    const float* wl   = (const float*)d_in[6];
    const float* wr   = (const float*)d_in[7];
    const float* Wres = (const float*)d_in[8];
    float* out = (float*)d_out;

    char* ws = (char*)d_ws;
    float* feat    = (float*)(ws + 0);
    float* resid   = (float*)(ws + 10240000);
    float* a_self  = (float*)(ws + 20480000);
    float* a_nb    = (float*)(ws + 20560000);
    int*   deg     = (int*)(ws + 20640000);
    int*   rowptr  = (int*)(ws + 20688000);
    int*   csr_src = (int*)(ws + 20784000);
    unsigned short* feat_b16 = (unsigned short*)(ws + 23344000);
    int*   bh      = (int*)(ws + 28464000);

    float* phis = out + (size_t)N_NODES * 2 * DIM;

    // zero a_self+a_nb (contiguous 160KB) and phis
    hipMemsetAsync(a_self, 0, 4 * N_NODES * sizeof(float), stream);
    hipMemsetAsync(phis, 0, N_GRAPHS * 2 * DIM * sizeof(float), stream);

    // fused GEMM + histogram (hist rides in grid-z slice 4)
    gemm_hist<<<dim3((N_NODES + 63) / 64, 2, 5), 256, 0, stream>>>(
        x, Wfc, bfc, Wres, feat, resid, feat_b16, wl, wr, a_self, a_nb,
        (const int4*)edst, bh);

    csr_node_scan<<<(N_NODES + 127) / 128, 128, 0, stream>>>(bh, deg);
    scan_deg<<<1, 1024, 0, stream>>>(deg, rowptr);
    csr_scatter<<<NB_CSR, 512, 0, stream>>>(
        (const int4*)esrc, (const int4*)edst, rowptr, bh, csr_src);

    aggregate<<<dim3(2500, 2), 256, 0, stream>>>(
        feat_b16, resid, a_self, a_nb, rowptr, csr_src, out);
    pool_graphs<<<dim3(N_GRAPHS, 16), 256, 0, stream>>>(out, gids, phis);
}

// Round 3
// 178.637 us; speedup vs baseline: 1.4398x; 1.1106x over previous
//
#include <hip/hip_runtime.h>
#include <hip/hip_bf16.h>
#include <math.h>

#define N_NODES 10000
#define N_EDGES 640000
#define N_GRAPHS 64
#define DIM 128
#define NEG_SLOPE 0.01f
#define NB_CSR 128            // histogram partitions (5000 edges each)
#define EDGES_PER_BLK (N_EDGES / NB_CSR)

// ---------------- workspace layout (bytes) ----------------
// feat     : 0          .. 10,240,000   (UNUSED now - kept for layout stability)
// resid    : 10,240,000 .. 20,480,000   float[2][10000][128]
// a_self   : 20,480,000                 float[2][10000]
// a_nb     : 20,560,000                 float[2][10000]
// deg      : 20,640,000                 int[10000]
// rowptr   : 20,688,000                 int[10001]
// csr_src  : 20,784,000                 int[640000]
// feat_b16 : 23,344,000 .. 28,464,000   bf16[2][10000][128]
// bh       : 28,464,000 .. 33,584,000   int[128][10000] (hist -> in-place excl. offsets)

__device__ __forceinline__ unsigned short f2bf(float f) {
    __hip_bfloat16 h = __float2bfloat16(f);
    return *reinterpret_cast<unsigned short*>(&h);
}

typedef __attribute__((ext_vector_type(8))) short short8v;  // 8 bf16 in 4 VGPR
typedef __attribute__((ext_vector_type(4))) float f32x4;

// ---------------- CSR build: phase 1, per-partition LDS histogram ----------------
__global__ __launch_bounds__(512) void csr_hist(const int4* __restrict__ edst4,
                                                int* __restrict__ bh) {
    __shared__ int hist[N_NODES];
    const int blk = blockIdx.x;
    const int t = threadIdx.x;
    for (int n = t; n < N_NODES; n += 512) hist[n] = 0;
    __syncthreads();
    const int base4 = blk * (EDGES_PER_BLK / 4);
    for (int i = t; i < EDGES_PER_BLK / 4; i += 512) {
        int4 d = edst4[base4 + i];
        atomicAdd(&hist[d.x], 1);
        atomicAdd(&hist[d.y], 1);
        atomicAdd(&hist[d.z], 1);
        atomicAdd(&hist[d.w], 1);
    }
    __syncthreads();
    int* dst = bh + (size_t)blk * N_NODES;
    for (int n = t; n < N_NODES; n += 512) dst[n] = hist[n];
}

// ---------------- CSR build: phase 2, per-node scan over partitions ----------------
__global__ __launch_bounds__(256) void csr_node_scan(int* __restrict__ bh,
                                                     int* __restrict__ deg) {
    int n = blockIdx.x * 256 + threadIdx.x;
    if (n >= N_NODES) return;
    int running = 0;
    for (int blk = 0; blk < NB_CSR; ++blk) {
        int* p = bh + (size_t)blk * N_NODES + n;
        int v = *p;
        *p = running;
        running += v;
    }
    deg[n] = running;
}

// ---------------- CSR build: phase 3, rowptr scan ----------------
__global__ __launch_bounds__(1024) void scan_deg(const int* __restrict__ deg,
                                                 int* __restrict__ rowptr) {
    __shared__ int sdata[1024];
    const int tid = threadIdx.x;
    const int base = tid * 10;
    int cnt = N_NODES - base;
    if (cnt < 0) cnt = 0;
    if (cnt > 10) cnt = 10;
    int local[10];
    int s = 0;
    for (int i = 0; i < cnt; ++i) { local[i] = s; s += deg[base + i]; }
    sdata[tid] = s;
    __syncthreads();
    for (int off = 1; off < 1024; off <<= 1) {
        int v = 0;
        if (tid >= off) v = sdata[tid - off];
        __syncthreads();
        if (tid >= off) sdata[tid] += v;
        __syncthreads();
    }
    int pre = (tid == 0) ? 0 : sdata[tid - 1];
    for (int i = 0; i < cnt; ++i) rowptr[base + i] = pre + local[i];
    if (tid == 1023) rowptr[N_NODES] = sdata[1023];
}

// ---------------- CSR build: phase 4, scatter via LDS cursors ----------------
__global__ __launch_bounds__(512) void csr_scatter(
    const int4* __restrict__ esrc4, const int4* __restrict__ edst4,
    const int* __restrict__ rowptr, const int* __restrict__ bh,
    int* __restrict__ csr_src) {
    __shared__ int cur[N_NODES];
    const int blk = blockIdx.x;
    const int t = threadIdx.x;
    const int* boff = bh + (size_t)blk * N_NODES;
    for (int n = t; n < N_NODES; n += 512) cur[n] = rowptr[n] + boff[n];
    __syncthreads();
    const int base4 = blk * (EDGES_PER_BLK / 4);
    for (int i = t; i < EDGES_PER_BLK / 4; i += 512) {
        int4 s = esrc4[base4 + i];
        int4 d = edst4[base4 + i];
        csr_src[atomicAdd(&cur[d.x], 1)] = s.x;
        csr_src[atomicAdd(&cur[d.y], 1)] = s.y;
        csr_src[atomicAdd(&cur[d.z], 1)] = s.z;
        csr_src[atomicAdd(&cur[d.w], 1)] = s.w;
    }
}

// ---------------- MFMA GEMM: feat_b16 / resid for all 4 (which,b) combos -------
// grid (157, 4), block 256 = 4 waves.  y: bit0 = which (0=feat_b16, 1=resid),
// bit1 = gat block.  Tile: 64 rows x 128 cols, full K=128 staged once.
// A = x[n][k] bf16, B = W[j][k] bf16 (nn.Linear layout == B^T form), fp32 accum.
// mfma_f32_16x16x32_bf16 layouts: A row=lane&15, k=(lane>>4)*8+i;
// B col=lane&15, k=(lane>>4)*8+i; D col=lane&15, row=(lane>>4)*4+reg.
#define LDK 136   // padded LDS row (bf16): stride 272B -> bank-balanced b128 reads
__global__ __launch_bounds__(256) void gemm_mfma(
    const float* __restrict__ x, const float* __restrict__ Wfc,
    const float* __restrict__ bfc, const float* __restrict__ Wres,
    float* __restrict__ resid, unsigned short* __restrict__ feat_b16) {
    __shared__ unsigned short xs[64 * LDK];     // 17,408 B
    __shared__ unsigned short wsh[128 * LDK];   // 34,816 B
    const int which = blockIdx.y & 1;
    const int b = blockIdx.y >> 1;
    const float* __restrict__ W = (which ? Wres : Wfc) + (size_t)b * DIM * DIM;
    const int n0 = blockIdx.x * 64;
    const int t = threadIdx.x;

    {   // stage x: 64 rows; thread t -> row t>>2, k-quarter (t&3)*32
        const int r = t >> 2;
        const int kq = (t & 3) * 32;
        const int n = n0 + r;
        unsigned short tmp[32];
        if (n < N_NODES) {
            const float4* px = reinterpret_cast<const float4*>(x + (size_t)n * DIM + kq);
#pragma unroll
            for (int i = 0; i < 8; ++i) {
                float4 v = px[i];
                tmp[4 * i]     = f2bf(v.x);
                tmp[4 * i + 1] = f2bf(v.y);
                tmp[4 * i + 2] = f2bf(v.z);
                tmp[4 * i + 3] = f2bf(v.w);
            }
        } else {
#pragma unroll
            for (int i = 0; i < 32; ++i) tmp[i] = 0;
        }
#pragma unroll
        for (int i = 0; i < 4; ++i)
            *reinterpret_cast<short8v*>(&xs[r * LDK + kq + 8 * i]) =
                *reinterpret_cast<const short8v*>(&tmp[8 * i]);
    }
    {   // stage W: 128 rows; thread t -> row t>>1, k-half (t&1)*64
        const int r = t >> 1;
        const int kh = (t & 1) * 64;
        const float4* pw = reinterpret_cast<const float4*>(W + (size_t)r * DIM + kh);
        unsigned short tmp[64];
#pragma unroll
        for (int i = 0; i < 16; ++i) {
            float4 v = pw[i];
            tmp[4 * i]     = f2bf(v.x);
            tmp[4 * i + 1] = f2bf(v.y);
            tmp[4 * i + 2] = f2bf(v.z);
            tmp[4 * i + 3] = f2bf(v.w);
        }
#pragma unroll
        for (int i = 0; i < 8; ++i)
            *reinterpret_cast<short8v*>(&wsh[r * LDK + kh + 8 * i]) =
                *reinterpret_cast<const short8v*>(&tmp[8 * i]);
    }
    __syncthreads();

    const int wave = t >> 6;
    const int lane = t & 63;
    const int l16 = lane & 15;
    const int l4 = lane >> 4;

    f32x4 acc[8];
#pragma unroll
    for (int nf = 0; nf < 8; ++nf) acc[nf] = (f32x4){0.f, 0.f, 0.f, 0.f};

    const int arow = wave * 16 + l16;
#pragma unroll
    for (int ks = 0; ks < 4; ++ks) {
        short8v af = *reinterpret_cast<const short8v*>(
            &xs[arow * LDK + ks * 32 + l4 * 8]);
#pragma unroll
        for (int nf = 0; nf < 8; ++nf) {
            short8v bfr = *reinterpret_cast<const short8v*>(
                &wsh[(nf * 16 + l16) * LDK + ks * 32 + l4 * 8]);
            acc[nf] = __builtin_amdgcn_mfma_f32_16x16x32_bf16(af, bfr, acc[nf], 0, 0, 0);
        }
    }

    const int rbase = n0 + wave * 16 + l4 * 4;
    if (which == 0) {
#pragma unroll
        for (int nf = 0; nf < 8; ++nf) {
            const float bias = bfc[b * DIM + nf * 16 + l16];
            unsigned short* dst = feat_b16 + (size_t)b * N_NODES * DIM + nf * 16 + l16;
#pragma unroll
            for (int r = 0; r < 4; ++r) {
                int n = rbase + r;
                if (n < N_NODES) dst[(size_t)n * DIM] = f2bf(acc[nf][r] + bias);
            }
        }
    } else {
        float* dst0 = resid + (size_t)b * N_NODES * DIM;
#pragma unroll
        for (int nf = 0; nf < 8; ++nf) {
#pragma unroll
            for (int r = 0; r < 4; ++r) {
                int n = rbase + r;
                if (n < N_NODES) dst0[(size_t)n * DIM + nf * 16 + l16] = acc[nf][r];
            }
        }
    }
}

// ---------------- attention scalars: a_self/a_nb exact in fp32 ----------------
// a_self[b][n] = x[n]·(Wfc_b^T wl_b) + bfc_b·wl_b   (and wr for a_nb).
// Each block redundantly computes the 4 u-vectors (tiny, L2-cached), then one
// thread per node does 4 dot products. Replaces the old GEMM-epilogue atomics.
__global__ __launch_bounds__(256) void attn_vec(
    const float* __restrict__ x, const float* __restrict__ Wfc,
    const float* __restrict__ bfc,
    const float* __restrict__ wl, const float* __restrict__ wr,
    float* __restrict__ a_self, float* __restrict__ a_nb) {
    __shared__ float u[2][2][DIM];   // [vec(self/nb)][b][k]
    __shared__ float c[2][2];
    const int t = threadIdx.x;
    for (int o = t; o < 512; o += 256) {
        int k = o & 127;
        int bb = (o >> 7) & 1;
        int v = o >> 8;
        const float* wv = (v ? wr : wl) + bb * DIM;
        const float* Wb = Wfc + (size_t)bb * DIM * DIM;
        float s = 0.f;
#pragma unroll 4
        for (int j = 0; j < DIM; ++j) s += wv[j] * Wb[j * DIM + k];
        u[v][bb][k] = s;
    }
    if (t < 4) {
        int v = t >> 1, bb = t & 1;
        const float* wv = (v ? wr : wl) + bb * DIM;
        const float* bias = bfc + bb * DIM;
        float s = 0.f;
        for (int j = 0; j < DIM; ++j) s += wv[j] * bias[j];
        c[v][bb] = s;
    }
    __syncthreads();
    int n = blockIdx.x * 256 + t;
    if (n >= N_NODES) return;
    const float4* px = reinterpret_cast<const float4*>(x + (size_t)n * DIM);
    float s00 = 0.f, s01 = 0.f, s10 = 0.f, s11 = 0.f;
#pragma unroll 8
    for (int i = 0; i < 32; ++i) {
        float4 v = px[i];
        const float* u00 = &u[0][0][4 * i];
        const float* u01 = &u[0][1][4 * i];
        const float* u10 = &u[1][0][4 * i];
        const float* u11 = &u[1][1][4 * i];
        s00 += v.x * u00[0] + v.y * u00[1] + v.z * u00[2] + v.w * u00[3];
        s01 += v.x * u01[0] + v.y * u01[1] + v.z * u01[2] + v.w * u01[3];
        s10 += v.x * u10[0] + v.y * u10[1] + v.z * u10[2] + v.w * u10[3];
        s11 += v.x * u11[0] + v.y * u11[1] + v.z * u11[2] + v.w * u11[3];
    }
    a_self[n] = s00 + c[0][0];
    a_self[N_NODES + n] = s01 + c[0][1];
    a_nb[n] = s10 + c[1][0];
    a_nb[N_NODES + n] = s11 + c[1][1];
}

// ---------------- softmax + weighted aggregation + residual + relu ----------------
// grid (2500, 2), block 256 = 4 waves, one node per wave. Single pass (no max:
// scores bounded ~|s|<20 << 88, exp(s) safe in fp32; softmax shift-invariant).
__global__ __launch_bounds__(256) void aggregate(
    const unsigned short* __restrict__ feat_b16, const float* __restrict__ resid,
    const float* __restrict__ a_self, const float* __restrict__ a_nb,
    const int* __restrict__ rowptr, const int* __restrict__ csr_src,
    float* __restrict__ out) {
    const int wave = threadIdx.x >> 6;
    const int lane = threadIdx.x & 63;
    const int n = blockIdx.x * 4 + wave;
    const int b = blockIdx.y;
    const int q = lane >> 4;     // edge slot within group of 4
    const int l16 = lane & 15;   // covers channels [l16*8, l16*8+8)
    const int start = rowptr[n];
    const int end = rowptr[n + 1];

    const float* __restrict__ anb = a_nb + b * N_NODES;
    const uint4* __restrict__ fb =
        reinterpret_cast<const uint4*>(feat_b16 + (size_t)b * N_NODES * DIM);
    const float asl = a_self[b * N_NODES + n];

    float acc[8];
#pragma unroll
    for (int k = 0; k < 8; ++k) acc[k] = 0.f;
    float dpart = 0.f;

    for (int c = start; c < end; c += 64) {
        int j = c + lane;
        float e = 0.f;
        int src = 0;
        if (j < end) {
            src = csr_src[j];
            float s = asl + anb[src];
            s = (s >= 0.f) ? s : NEG_SLOPE * s;
            e = __expf(s);
        }
        dpart += e;
        int cnt = end - c;
        if (cnt > 64) cnt = 64;
        int iters = (cnt + 3) >> 2;

        float w0 = __shfl(e, q, 64);
        int s0 = __shfl(src, q, 64);
        uint4 f0 = fb[(size_t)s0 * 16 + l16];

        for (int i2 = 0; i2 < iters - 1; ++i2) {
            int idx = (i2 + 1) * 4 + q;
            float w1 = __shfl(e, idx, 64);
            int s1 = __shfl(src, idx, 64);
            uint4 f1 = fb[(size_t)s1 * 16 + l16];
#pragma unroll
            for (int k = 0; k < 4; ++k) {
                unsigned int u = (&f0.x)[k];
                float lo = __uint_as_float(u << 16);
                float hi = __uint_as_float(u & 0xffff0000u);
                acc[2 * k]     += w0 * lo;
                acc[2 * k + 1] += w0 * hi;
            }
            w0 = w1; f0 = f1;
        }
#pragma unroll
        for (int k = 0; k < 4; ++k) {
            unsigned int u = (&f0.x)[k];
            float lo = __uint_as_float(u << 16);
            float hi = __uint_as_float(u & 0xffff0000u);
            acc[2 * k]     += w0 * lo;
            acc[2 * k + 1] += w0 * hi;
        }
    }

#pragma unroll
    for (int k = 0; k < 8; ++k) {
        acc[k] += __shfl_xor(acc[k], 16, 64);
        acc[k] += __shfl_xor(acc[k], 32, 64);
    }
    float denom = dpart;
#pragma unroll
    for (int off = 32; off > 0; off >>= 1) denom += __shfl_xor(denom, off, 64);

    if (q == 0) {
        float inv = (end > start) ? 1.f / denom : 0.f;
        const float4* rr = reinterpret_cast<const float4*>(
            resid + ((size_t)b * N_NODES + n) * DIM);
        float4 r0 = rr[l16 * 2];
        float4 r1 = rr[l16 * 2 + 1];
        float4 o0, o1;
        o0.x = fmaxf(acc[0] * inv + r0.x, 0.f);
        o0.y = fmaxf(acc[1] * inv + r0.y, 0.f);
        o0.z = fmaxf(acc[2] * inv + r0.z, 0.f);
        o0.w = fmaxf(acc[3] * inv + r0.w, 0.f);
        o1.x = fmaxf(acc[4] * inv + r1.x, 0.f);
        o1.y = fmaxf(acc[5] * inv + r1.y, 0.f);
        o1.z = fmaxf(acc[6] * inv + r1.z, 0.f);
        o1.w = fmaxf(acc[7] * inv + r1.w, 0.f);
        float4* po = reinterpret_cast<float4*>(out + (size_t)n * (2 * DIM) + b * DIM);
        po[l16 * 2] = o0;
        po[l16 * 2 + 1] = o1;
    }
}

// ---------------- per-graph sum pooling ----------------
__device__ int lower_bound_dev(const int* __restrict__ a, int n, int key) {
    int lo = 0, hi = n;
    while (lo < hi) {
        int mid = (lo + hi) >> 1;
        if (a[mid] < key) lo = mid + 1;
        else hi = mid;
    }
    return lo;
}

__global__ __launch_bounds__(256) void pool_graphs(
    const float* __restrict__ h, const int* __restrict__ gids,
    float* __restrict__ phis) {
    const int g = blockIdx.x;
    const int chunk = blockIdx.y;
    const int tid = threadIdx.x;
    int lo = lower_bound_dev(gids, N_NODES, g);
    int hi = lower_bound_dev(gids, N_NODES, g + 1);
    float acc = 0.f;
    for (int n = lo + chunk; n < hi; n += 16) acc += h[(size_t)n * (2 * DIM) + tid];
    if (acc != 0.f) atomicAdd(&phis[(size_t)g * (2 * DIM) + tid], acc);
}

extern "C" void kernel_launch(void* const* d_in, const int* in_sizes, int n_in,
                              void* d_out, int out_size, void* d_ws, size_t ws_size,
                              hipStream_t stream) {
    const float* x    = (const float*)d_in[0];
    const int* esrc   = (const int*)d_in[1];
    const int* edst   = (const int*)d_in[2];
    const int* gids   = (const int*)d_in[3];
    const float* Wfc  = (const float*)d_in[4];
    const float* bfc  = (const float*)d_in[5];
    const float* wl   = (const float*)d_in[6];
    const float* wr   = (const float*)d_in[7];
    const float* Wres = (const float*)d_in[8];
    float* out = (float*)d_out;

    char* ws = (char*)d_ws;
    float* resid   = (float*)(ws + 10240000);
    float* a_self  = (float*)(ws + 20480000);
    float* a_nb    = (float*)(ws + 20560000);
    int*   deg     = (int*)(ws + 20640000);
    int*   rowptr  = (int*)(ws + 20688000);
    int*   csr_src = (int*)(ws + 20784000);
    unsigned short* feat_b16 = (unsigned short*)(ws + 23344000);
    int*   bh      = (int*)(ws + 28464000);

    float* phis = out + (size_t)N_NODES * 2 * DIM;

    // phis accumulated via atomics -> zero it. a_self/a_nb now written directly.
    hipMemsetAsync(phis, 0, N_GRAPHS * 2 * DIM * sizeof(float), stream);

    attn_vec<<<(N_NODES + 255) / 256, 256, 0, stream>>>(
        x, Wfc, bfc, wl, wr, a_self, a_nb);

    csr_hist<<<NB_CSR, 512, 0, stream>>>((const int4*)edst, bh);
    csr_node_scan<<<(N_NODES + 255) / 256, 256, 0, stream>>>(bh, deg);
    scan_deg<<<1, 1024, 0, stream>>>(deg, rowptr);
    csr_scatter<<<NB_CSR, 512, 0, stream>>>(
        (const int4*)esrc, (const int4*)edst, rowptr, bh, csr_src);

    gemm_mfma<<<dim3((N_NODES + 63) / 64, 4), 256, 0, stream>>>(
        x, Wfc, bfc, Wres, resid, feat_b16);

    aggregate<<<dim3(2500, 2), 256, 0, stream>>>(
        feat_b16, resid, a_self, a_nb, rowptr, csr_src, out);
    pool_graphs<<<dim3(N_GRAPHS, 16), 256, 0, stream>>>(out, gids, phis);
}